// Round 9
// baseline (226.105 us; speedup 1.0000x reference)
//
#include <hip/hip_runtime.h>
#include <cstdint>

typedef unsigned long long u64;
typedef unsigned int u32;

#define B_ 4
#define N_ 3600
#define C_ 16
#define NW_ 57        // ceil(N/64) words of adjacency/valid bitmask
#define NPAD_ 3648    // NW_*64
#define RPW_ 6        // rows per wave (k_adj)
#define RPB_ 24       // rows per block (k_adj, 4 waves); N_/RPB_ = 150
#define NBLK_ 15      // k_valid: blocks per image (15*256 = 3840 >= N)

// ---------------------------------------------------------------------------
// K1: adjacency bitmask. 6 rows/wave, 24 rows/block; all 3648 boxes staged in
// LDS once (58.4 KB). Lane t holds row word t in a register -> one contiguous
// 456 B store per row. 6 independent row-chains/wave hide VALU latency.
//
// Exact division-free IoU test:
//   round_f32(inter/denom) >= 0.4f  <=>  inter > (0.4f - 2^-26)*denom in f64
//   (26x24-bit mantissa product is exact; midpoint ties round-to-even to
//   prev(0.4f) < 0.4f -> false, matching strict '>'). denom==0 => inter==0
//   => false, matching 0/0=NaN >= 0.4 false. Zero-padded boxes => false.
// ---------------------------------------------------------------------------
__global__ __launch_bounds__(256, 2) void k_adj(const float* __restrict__ boxes,
                                                u64* __restrict__ adj) {
#pragma clang fp contract(off)
    __shared__ float4 sbox[NPAD_];   // (x1,y1,x2,y2)
    const int tid  = threadIdx.x;
    const int lane = tid & 63;
    const int wv   = tid >> 6;
    const int g    = blockIdx.x;                 // 0 .. B*150-1
    const int b    = g / (N_ / RPB_);
    const int r0   = (g % (N_ / RPB_)) * RPB_ + wv * RPW_;
    const size_t bN = (size_t)b * N_;

    for (int j = tid; j < NPAD_; j += 256) {
        float x1 = 0.f, y1 = 0.f, x2 = 0.f, y2 = 0.f;
        if (j < N_) {
            const float4 bx = reinterpret_cast<const float4*>(boxes)[bN + j];
            x1 = bx.x - bx.z * 0.5f;   // cx - w/2 (reference op order)
            y1 = bx.y - bx.w * 0.5f;
            x2 = x1 + bx.z;
            y2 = y1 + bx.w;
        }
        sbox[j] = make_float4(x1, y1, x2, y2);
    }
    __syncthreads();

    float4 bi[RPW_];
    float  ai[RPW_];
#pragma unroll
    for (int r = 0; r < RPW_; ++r) {
        bi[r] = sbox[r0 + r];
        ai[r] = (bi[r].z - bi[r].x) * (bi[r].w - bi[r].y);
    }
    const double MID = (double)0.4f - 0x1p-26;   // exact

    u64 row[RPW_];
#pragma unroll
    for (int r = 0; r < RPW_; ++r) row[r] = 0ull;

    for (int t = 0; t < NW_; ++t) {
        const int    j  = t * 64 + lane;
        const float4 bj = sbox[t * 64 + lane];
        const float ajr = (bj.z - bj.x) * (bj.w - bj.y);
#pragma unroll
        for (int r = 0; r < RPW_; ++r) {
            const float ltx = fmaxf(bi[r].x, bj.x);
            const float lty = fmaxf(bi[r].y, bj.y);
            const float rbx = fminf(bi[r].z, bj.z);
            const float rby = fminf(bi[r].w, bj.w);
            const float whx = fmaxf(rbx - ltx, 0.0f);
            const float why = fmaxf(rby - lty, 0.0f);
            const float inter = whx * why;
            const float denom = (ai[r] + ajr) - inter;
            const int pred = ((double)inter > MID * (double)denom) && (j != r0 + r);
            const u64 m = __ballot(pred);
            if (lane == t) row[r] = m;           // 2x v_cndmask
        }
    }

#pragma unroll
    for (int r = 0; r < RPW_; ++r)
        if (lane < NW_) adj[(bN + r0 + r) * (size_t)NW_ + lane] = row[r];
}

// ---------------------------------------------------------------------------
// K1b: sparse threshold kernel. One wave per row: lane w iterates its adj
// word's set bits, gathers con[j][0..15], fmax-accumulates; 6-step shuffle
// max-reduce; thr[i][c] = max(adj_con, con_i). Exact: p>=a && p>=b <=>
// p >= fmax(a,b) for non-NaN; adj_con init 0 matches where(adj, con, 0).
// ---------------------------------------------------------------------------
__global__ __launch_bounds__(256) void k_acon(const u64* __restrict__ adj,
                                              const float* __restrict__ con,
                                              float* __restrict__ thr) {
    const int tid  = threadIdx.x;
    const int lane = tid & 63;
    const int wv   = tid >> 6;
    const int g    = blockIdx.x;                 // 0 .. B*N/4-1
    const int b    = g / (N_ / 4);
    const int i    = (g % (N_ / 4)) * 4 + wv;
    const size_t bN = (size_t)b * N_;

    u64 w = (lane < NW_) ? adj[(bN + i) * (size_t)NW_ + lane] : 0ull;

    float cm[C_];
#pragma unroll
    for (int k = 0; k < C_; ++k) cm[k] = 0.0f;

    while (w) {
        const int bit = __builtin_ctzll(w); w &= w - 1;
        const int j   = lane * 64 + bit;
        const float4* cp = reinterpret_cast<const float4*>(con + (bN + j) * C_);
        const float4 c0 = cp[0], c1 = cp[1], c2 = cp[2], c3 = cp[3];
        cm[0]  = fmaxf(cm[0],  c0.x); cm[1]  = fmaxf(cm[1],  c0.y);
        cm[2]  = fmaxf(cm[2],  c0.z); cm[3]  = fmaxf(cm[3],  c0.w);
        cm[4]  = fmaxf(cm[4],  c1.x); cm[5]  = fmaxf(cm[5],  c1.y);
        cm[6]  = fmaxf(cm[6],  c1.z); cm[7]  = fmaxf(cm[7],  c1.w);
        cm[8]  = fmaxf(cm[8],  c2.x); cm[9]  = fmaxf(cm[9],  c2.y);
        cm[10] = fmaxf(cm[10], c2.z); cm[11] = fmaxf(cm[11], c2.w);
        cm[12] = fmaxf(cm[12], c3.x); cm[13] = fmaxf(cm[13], c3.y);
        cm[14] = fmaxf(cm[14], c3.z); cm[15] = fmaxf(cm[15], c3.w);
    }

#pragma unroll
    for (int off = 1; off < 64; off <<= 1) {
#pragma unroll
        for (int k = 0; k < C_; ++k) cm[k] = fmaxf(cm[k], __shfl_xor(cm[k], off));
    }
    if (lane == 0) {
        const float4* cp = reinterpret_cast<const float4*>(con + (bN + i) * C_);
        const float4 c0 = cp[0], c1 = cp[1], c2 = cp[2], c3 = cp[3];
        float4* o = reinterpret_cast<float4*>(thr + (bN + i) * C_);
        o[0] = make_float4(fmaxf(cm[0],  c0.x), fmaxf(cm[1],  c0.y),
                           fmaxf(cm[2],  c0.z), fmaxf(cm[3],  c0.w));
        o[1] = make_float4(fmaxf(cm[4],  c1.x), fmaxf(cm[5],  c1.y),
                           fmaxf(cm[6],  c1.z), fmaxf(cm[7],  c1.w));
        o[2] = make_float4(fmaxf(cm[8],  c2.x), fmaxf(cm[9],  c2.y),
                           fmaxf(cm[10], c2.z), fmaxf(cm[11], c2.w));
        o[3] = make_float4(fmaxf(cm[12], c3.x), fmaxf(cm[13], c3.y),
                           fmaxf(cm[14], c3.z), fmaxf(cm[15], c3.w));
    }
}

// ---------------------------------------------------------------------------
// K2: coalesced valid0 + global compaction. One thread per box, all 16 c.
// Per class: wave ballot -> pvm word; unordered keyed scatter to keys_ws via
// one atomicAdd per (wave, c). Nondeterministic order is erased by k_main's
// sort (keys carry a total order: score bits desc + idx asc).
// ---------------------------------------------------------------------------
__global__ __launch_bounds__(256) void k_valid(const float* __restrict__ pro,
                                               const float* __restrict__ thr,
                                               const float* __restrict__ conf,
                                               u64* __restrict__ keys_ws,
                                               u64* __restrict__ pvm_ws,
                                               u32* __restrict__ tcnt) {
    const int tid  = threadIdx.x;
    const int lane = tid & 63;
    const int wv   = tid >> 6;
    const int b    = blockIdx.x / NBLK_;
    const int blk  = blockIdx.x % NBLK_;
    const int i    = blk * 256 + wv * 64 + lane;
    const size_t bN = (size_t)b * N_;
    const int inb  = (i < N_);
    const int word = blk * 4 + wv;               // 0..59; words >=57 unused

    float pv[C_], tv[C_];
    if (inb) {
        const float4* pp = reinterpret_cast<const float4*>(pro + (bN + i) * C_);
        const float4* tp = reinterpret_cast<const float4*>(thr + (bN + i) * C_);
#pragma unroll
        for (int k = 0; k < 4; ++k) {
            const float4 a = pp[k];
            pv[4*k] = a.x; pv[4*k+1] = a.y; pv[4*k+2] = a.z; pv[4*k+3] = a.w;
            const float4 t = tp[k];
            tv[4*k] = t.x; tv[4*k+1] = t.y; tv[4*k+2] = t.z; tv[4*k+3] = t.w;
        }
    } else {
#pragma unroll
        for (int k = 0; k < C_; ++k) { pv[k] = 0.f; tv[k] = 0.f; }
    }

#pragma unroll
    for (int c = 0; c < C_; ++c) {
        const float cf = conf[c];
        const int pred = inb && (pv[c] >= cf) && (pv[c] >= tv[c]);
        const u64 bm = __ballot(pred);
        const size_t bc = (size_t)b * C_ + c;
        if (lane == 0) pvm_ws[bc * 64 + word] = bm;
        u32 base = 0;
        if (lane == 0 && bm) base = atomicAdd(&tcnt[bc], (u32)__popcll(bm));
        base = (u32)__shfl((int)base, 0);
        if (pred) {
            const u32 pb_ = __float_as_uint(pv[c]);
            const u32 pk  = pb_ ^ ((pb_ >> 31) ? 0xFFFFFFFFu : 0x80000000u);
            keys_ws[bc * N_ + base + (u32)__popcll(bm & ((1ull << lane) - 1ull))]
                = (((u64)(~pk)) << 32) | (u32)i;
        }
    }
}

// ---------------------------------------------------------------------------
// K3: sort + single-barrier pipelined greedy + output. One block per (b,c).
// Wave 0 owns the valid bitmask in registers (lane w = word w): ext-check
// (2 bpermutes) -> sparse resolve over sintra (steps == accepted count) ->
// batched-8 apply (independent LDS reads). Waves 1-3 concurrently build
// sintra for chunk+1 (symmetric ballots) and stage chunk+2 rows (3-buffer
// LDS; buffer 2 aliases the dead sort-keys region). ONE barrier per chunk.
// Exactness: same accept rule as rounds 7/8 (reference greedy restricted to
// valid0; suppression only clears bits); survivors in greedy order ==
// reference's final sorted output (stable ties via idx key bits).
// ---------------------------------------------------------------------------
#define ARENA_KEYS   0
#define ARENA_BUF0   32768
#define ARENA_BUF1   (32768 + 29184)
#define ARENA_SIZE   (32768 + 2 * 29184)

__global__ __launch_bounds__(256, 1) void k_main(const u64* __restrict__ keys_ws,
                                                 const u64* __restrict__ pvm_ws,
                                                 const u32* __restrict__ tcnt,
                                                 const u64* __restrict__ adj,
                                                 const float* __restrict__ pro,
                                                 const float* __restrict__ boxes,
                                                 const float* __restrict__ scales,
                                                 float* __restrict__ out) {
#pragma clang fp contract(off)
    __shared__ __align__(16) char arena[ARENA_SIZE];
    __shared__ u32 sidx[NPAD_];
    __shared__ u32 slist[NPAD_];
    __shared__ u64 sintra[2][64];
    __shared__ u32 sacc[64];
    __shared__ u32 s_S;
    u64* keys = (u64*)(arena + ARENA_KEYS);
    u64* bufA[3];
    bufA[0] = (u64*)(arena + ARENA_BUF0);
    bufA[1] = (u64*)(arena + ARENA_BUF1);
    bufA[2] = (u64*)(arena + ARENA_KEYS);        // aliases keys (dead post-sort)

    const int tid  = threadIdx.x;
    const int lane = tid & 63;
    const int wv   = tid >> 6;
    const int bc   = blockIdx.x;
    const int b    = bc / C_, c = bc % C_;
    const size_t bN = (size_t)b * N_;

    const int T = (int)tcnt[bc];

    // --- load + sort keys (asc => score desc, idx asc) ---
    for (int x = tid; x < T; x += 256) keys[x] = keys_ws[(size_t)bc * N_ + x];
    int P = 2;
    while (P < T) P <<= 1;                       // P <= 4096
    for (int x = T + tid; x < P; x += 256) keys[x] = ~0ull;
    __syncthreads();
    for (int k = 2; k <= P; k <<= 1) {
        for (int j = k >> 1; j > 0; j >>= 1) {
            for (int t = tid; t < P; t += 256) {
                const int ixj = t ^ j;
                if (ixj > t) {
                    const u64 a = keys[t], bb = keys[ixj];
                    const bool up = ((t & k) == 0);
                    if ((a > bb) == up) { keys[t] = bb; keys[ixj] = a; }
                }
            }
            __syncthreads();
        }
    }
    for (int x = tid; x < T; x += 256) sidx[x] = (u32)(keys[x] & 0xFFFFFFFFull);
    __syncthreads();                             // keys dead; buf2 may reuse

    // --- stage chunks 0,1 ---
#pragma unroll
    for (int rr = 0; rr < 16; ++rr) {
        const int r = wv * 16 + rr;
        const u32 i0 = (r < T) ? sidx[r] : 0u;
        if (lane < NW_) bufA[0][(size_t)r * NW_ + lane] = adj[(bN + i0) * (size_t)NW_ + lane];
        const int q = 64 + r;
        const u32 i1 = (q < T) ? sidx[q] : 0u;
        if (lane < NW_) bufA[1][(size_t)r * NW_ + lane] = adj[(bN + i1) * (size_t)NW_ + lane];
    }
    __syncthreads();

    // --- build sintra[0] ---
    {
        const int cn0 = min(64, T);
#pragma unroll
        for (int rr = 0; rr < 16; ++rr) {
            const int r = wv * 16 + rr;
            const u32 idxr = (r < T) ? sidx[r] : 0u;
            const u64 rj = bufA[0][(size_t)lane * NW_ + (idxr >> 6)];
            const u64 ib = __ballot((lane < cn0) && ((rj >> (idxr & 63)) & 1ull));
            if (lane == 0) sintra[0][r] = (r < T) ? ib : 0ull;
        }
    }
    u64 myw = (lane < NW_) ? pvm_ws[(size_t)bc * 64 + lane] : 0ull;   // wave 0 uses
    __syncthreads();

    // --- chunk loop: ONE barrier per chunk ---
    u32 S = 0;                                   // wave 0 only
    const int NCH = (T + 63) >> 6;
    for (int ch = 0; ch < NCH; ++ch) {
        const int pb = ch & 1;
        const int c0 = ch << 6;
        const int cn = min(64, T - c0);
        u64* bufc = bufA[ch % 3];

        if (wv == 0) {
            // ext-check against myw (register-resident valid bitmask)
            const u32 idxme = (c0 + lane < T) ? sidx[c0 + lane] : 0u;
            const int wme = (int)(idxme >> 6);
            const u32 lo = (u32)__shfl((int)(u32)myw, wme);
            const u32 hi = (u32)__shfl((int)(u32)(myw >> 32), wme);
            const u32 sel = (idxme & 32) ? hi : lo;
            const int bit = (int)((sel >> (idxme & 31)) & 1u);
            u64 cv = __ballot((lane < cn) && bit);
            const u64 iv = sintra[pb][lane];
            const u32 ivLo = (u32)iv, ivHi = (u32)(iv >> 32);
            // sparse resolve: steps == accepted count
            u64 accept = 0ull;
            int na = 0;
            while (cv) {
                const int r = (int)__builtin_ctzll(cv);
                accept |= 1ull << r;
                if (lane == 0) sacc[na] = (u32)r;
                ++na;
                const u64 ir =
                    ((u64)(u32)__builtin_amdgcn_readlane((int)ivHi, r) << 32)
                  |  (u64)(u32)__builtin_amdgcn_readlane((int)ivLo, r);
                cv &= ~(ir | (1ull << r));
            }
            // emit survivors in greedy order
            if ((accept >> lane) & 1ull) {
                const u32 pos = S + (u32)__popcll(accept & ((1ull << lane) - 1ull));
                slist[pos] = idxme;
            }
            S += (u32)__popcll(accept);
            // batched-8 apply (independent LDS reads)
            const int l57 = (lane < NW_) ? lane : NW_ - 1;
            u64 acc = 0ull;
            for (int q0 = 0; q0 < na; q0 += 8) {
                const u32 r0 = sacc[q0];
                const u32 r1 = (q0 + 1 < na) ? sacc[q0 + 1] : r0;
                const u32 r2 = (q0 + 2 < na) ? sacc[q0 + 2] : r0;
                const u32 r3 = (q0 + 3 < na) ? sacc[q0 + 3] : r0;
                const u32 r4 = (q0 + 4 < na) ? sacc[q0 + 4] : r0;
                const u32 r5 = (q0 + 5 < na) ? sacc[q0 + 5] : r0;
                const u32 r6 = (q0 + 6 < na) ? sacc[q0 + 6] : r0;
                const u32 r7 = (q0 + 7 < na) ? sacc[q0 + 7] : r0;
                const u64 a0 = bufc[(size_t)r0 * NW_ + l57];
                const u64 a1 = bufc[(size_t)r1 * NW_ + l57];
                const u64 a2 = bufc[(size_t)r2 * NW_ + l57];
                const u64 a3 = bufc[(size_t)r3 * NW_ + l57];
                const u64 a4 = bufc[(size_t)r4 * NW_ + l57];
                const u64 a5 = bufc[(size_t)r5 * NW_ + l57];
                const u64 a6 = bufc[(size_t)r6 * NW_ + l57];
                const u64 a7 = bufc[(size_t)r7 * NW_ + l57];
                acc |= (a0 | a1) | (a2 | a3) | ((a4 | a5) | (a6 | a7));
            }
            if (lane < NW_) myw &= ~acc;
        } else {
            // builders: stage chunk ch+2, build sintra for chunk ch+1
            const int wq = wv - 1;               // 0..2
            const int have1 = (ch + 1 < NCH);
            const int have2 = (ch + 2 < NCH);
            const int cn1 = have1 ? min(64, T - ((ch + 1) << 6)) : 0;
            u64* bufn = bufA[(ch + 1) % 3];
            u64* buf2 = bufA[(ch + 2) % 3];
            u64 pre[22];
#pragma unroll
            for (int k = 0; k < 22; ++k) {
                const int r = wq + 3 * k;
                const int q = ((ch + 2) << 6) + r;
                const u32 idx2 = (have2 && r < 64 && q < T) ? sidx[q] : 0u;
                pre[k] = (have2 && r < 64 && lane < NW_)
                           ? adj[(bN + idx2) * (size_t)NW_ + lane] : 0ull;
            }
#pragma unroll
            for (int k = 0; k < 22; ++k) {
                const int r = wq + 3 * k;
                if (r < 64) {
                    const int q1 = ((ch + 1) << 6) + r;
                    const int liv = (have1 && q1 < T);
                    const u32 idxr = liv ? sidx[q1] : 0u;
                    const u64 rj = bufn[(size_t)lane * NW_ + (idxr >> 6)];
                    const u64 ib = __ballot((lane < cn1) && ((rj >> (idxr & 63)) & 1ull));
                    if (lane == 0) sintra[pb ^ 1][r] = liv ? ib : 0ull;
                }
            }
            if (have2) {
#pragma unroll
                for (int k = 0; k < 22; ++k) {
                    const int r = wq + 3 * k;
                    if (r < 64 && lane < NW_) buf2[(size_t)r * NW_ + lane] = pre[k];
                }
            }
        }
        __syncthreads();
    }
    if (wv == 0 && lane == 0) s_S = S;
    __syncthreads();

    // --- output survivors in greedy order (suppressed rows stay zeros) ---
    const int Sf = (int)s_S;
    const float s = scales[b];
    for (int r = tid; r < Sf; r += 256) {
        const int idx = (int)slist[r];
        const float4 bx = reinterpret_cast<const float4*>(boxes)[bN + idx];
        const float scx = bx.x * s, scy = bx.y * s, sw = bx.z * s, sh = bx.w * s;
        float* o = out + ((size_t)bc * N_ + r) * 5;
        o[0] = scx - 0.5f * sw;
        o[1] = scy - 0.5f * sh;
        o[2] = scx + 0.5f * sw;
        o[3] = scy + 0.5f * sh;
        o[4] = pro[(bN + idx) * C_ + c];
        out[(size_t)B_ * C_ * N_ * 5 + (size_t)bc * N_ + r] = 1.0f;
    }
}

// ---------------------------------------------------------------------------
extern "C" void kernel_launch(void* const* d_in, const int* in_sizes, int n_in,
                              void* d_out, int out_size, void* d_ws, size_t ws_size,
                              hipStream_t stream) {
    const float* pro    = (const float*)d_in[0];   // (B,N,C)
    const float* con    = (const float*)d_in[1];   // (B,N,C)
    const float* boxes  = (const float*)d_in[2];   // (B,N,4)
    const float* scales = (const float*)d_in[3];   // (B,)
    const float* conf   = (const float*)d_in[4];   // (C,)

    char* ws = (char*)d_ws;
    u64* adj = (u64*)ws;                                   // B*N*NW u64  (6.57 MB)
    size_t off = (size_t)B_ * N_ * NW_ * sizeof(u64);
    float* thr = (float*)(ws + off);                       // B*N*C f32   (0.92 MB)
    off += (size_t)B_ * N_ * C_ * sizeof(float);
    u64* keys_ws = (u64*)(ws + off);                       // B*C*N u64   (1.84 MB)
    off += (size_t)B_ * C_ * N_ * sizeof(u64);
    u64* pvm_ws = (u64*)(ws + off);                        // 64*64 u64   (32 KB)
    off += (size_t)B_ * C_ * 64 * sizeof(u64);
    u32* tcnt = (u32*)(ws + off);                          // 64 u32

    hipMemsetAsync(d_out, 0, (size_t)out_size * sizeof(float), stream);
    hipMemsetAsync(tcnt, 0, B_ * C_ * sizeof(u32), stream);
    k_adj  <<<B_ * N_ / RPB_, 256, 0, stream>>>(boxes, adj);
    k_acon <<<B_ * N_ / 4,    256, 0, stream>>>(adj, con, thr);
    k_valid<<<B_ * NBLK_,     256, 0, stream>>>(pro, thr, conf, keys_ws, pvm_ws, tcnt);
    k_main <<<B_ * C_,        256, 0, stream>>>(keys_ws, pvm_ws, tcnt, adj, pro,
                                                boxes, scales, (float*)d_out);
}